// Round 5
// baseline (44.333 us; speedup 1.0000x reference)
//
#include <hip/hip_runtime.h>

// out[i] = action_embed[i] . t[b(i)],  t = state_embed @ (wq @ wk^T),  b(i) = rev_idx[i]/20
//
// Separate kernels (round-4 fusion was latency-bound at 4 blocks/CU; the
// 105 MB stream needs deep TLP, the GEMM needs full-GPU width):
// K1: M = wq @ wk^T                    (128x128, tiny)
// K2: t = state @ M                    (512 blocks x 32 rows; wave->8 rows,
//                                       lane->2 cols; round-3-proven tiling)
// K3: out[i] = dot(action[i], t[b])    (6400 blocks, 1 task/thread, 25 blk/CU)

__global__ __launch_bounds__(256) void k1_weights(const float* __restrict__ wq,
                                                  const float* __restrict__ wk,
                                                  float* __restrict__ M) {
    int idx = blockIdx.x * 256 + threadIdx.x;    // 0..16383
    int d = idx >> 7, e = idx & 127;
    const float4* q4 = reinterpret_cast<const float4*>(wq + (size_t)d * 128);
    const float4* w4 = reinterpret_cast<const float4*>(wk + (size_t)e * 128);
    float acc = 0.f;
#pragma unroll
    for (int k = 0; k < 32; ++k) {
        float4 a = q4[k], b = w4[k];
        acc += a.x * b.x + a.y * b.y + a.z * b.z + a.w * b.w;
    }
    M[idx] = acc;
}

constexpr int RPB  = 32;    // rows per block in k2
constexpr int SSTR = 132;   // padded LDS row stride (floats), 16B-aligned

__global__ __launch_bounds__(256) void k2_t(const float* __restrict__ state,
                                            const float* __restrict__ M,
                                            float* __restrict__ t) {
    __shared__ float sS[RPB * SSTR];
    const int tid = threadIdx.x;
    const int r0b = blockIdx.x * RPB;

    // stage state rows [32][128] (4096 floats, 4 x float4 per thread)
#pragma unroll
    for (int rep = 0; rep < 4; ++rep) {
        int f = (rep * 256 + tid) * 4;
        int g = f >> 7, d = f & 127;
        float4 v = *reinterpret_cast<const float4*>(state + (size_t)(r0b + g) * 128 + d);
        *reinterpret_cast<float4*>(sS + g * SSTR + d) = v;
    }
    __syncthreads();

    // wave w -> rows w*8..w*8+7; lane -> cols e0, e0+1 (float2 M loads,
    // 64 lanes x 8B = 512B/instr). state rows via wave-uniform b128 broadcast.
    const int w  = tid >> 6;
    const int e0 = (tid & 63) * 2;
    float a0[8], a1[8];
#pragma unroll
    for (int i = 0; i < 8; ++i) { a0[i] = 0.f; a1[i] = 0.f; }
    for (int d4 = 0; d4 < 128; d4 += 4) {
        float4 s[8];
#pragma unroll
        for (int i = 0; i < 8; ++i)
            s[i] = *reinterpret_cast<const float4*>(sS + (w * 8 + i) * SSTR + d4);
#pragma unroll
        for (int dd = 0; dd < 4; ++dd) {
            float2 m = *reinterpret_cast<const float2*>(M + (size_t)(d4 + dd) * 128 + e0);
#pragma unroll
            for (int i = 0; i < 8; ++i) {
                float sv = (dd == 0) ? s[i].x : (dd == 1) ? s[i].y : (dd == 2) ? s[i].z : s[i].w;
                a0[i] += sv * m.x;
                a1[i] += sv * m.y;
            }
        }
    }
#pragma unroll
    for (int i = 0; i < 8; ++i)
        *reinterpret_cast<float2*>(t + (size_t)(r0b + w * 8 + i) * 128 + e0) =
            make_float2(a0[i], a1[i]);
}

// K3: 8 lanes per node; lane ln covers d = ln*4 + 32*i (i=0..3); shfl-xor reduce.
__global__ __launch_bounds__(256) void k3_scores(const float* __restrict__ action,
                                                 const float* __restrict__ t,
                                                 const int* __restrict__ rev,
                                                 float* __restrict__ out,
                                                 int n_nodes) {
    int g = blockIdx.x * 256 + threadIdx.x;
    int node = g >> 3, ln = g & 7;
    if (node >= n_nodes) return;
    int b = rev[node] / 20;
    const float* arow = action + (size_t)node * 128;
    const float* trow = t + (size_t)b * 128;
    float acc = 0.f;
#pragma unroll
    for (int i = 0; i < 4; ++i) {
        int d = ln * 4 + i * 32;
        float4 a = *reinterpret_cast<const float4*>(arow + d);
        float4 x = *reinterpret_cast<const float4*>(trow + d);
        acc += a.x * x.x + a.y * x.y + a.z * x.z + a.w * x.w;
    }
    acc += __shfl_xor(acc, 1);
    acc += __shfl_xor(acc, 2);
    acc += __shfl_xor(acc, 4);
    if (ln == 0) out[node] = acc;
}

extern "C" void kernel_launch(void* const* d_in, const int* in_sizes, int n_in,
                              void* d_out, int out_size, void* d_ws, size_t ws_size,
                              hipStream_t stream) {
    const float* state  = (const float*)d_in[0];   // [B,128] f32
    const float* action = (const float*)d_in[1];   // [total,128] f32
    const float* wq     = (const float*)d_in[2];   // [128,128] f32
    const float* wk     = (const float*)d_in[3];   // [128,128] f32
    const int*   rev    = (const int*)d_in[6];     // [total] i32
    float* out = (float*)d_out;

    const int B = in_sizes[0] / 128;               // 16384
    const int n_nodes = in_sizes[6];               // 204800

    float* M = (float*)d_ws;                       // 64 KB
    float* t = (float*)((char*)d_ws + 65536);      // B*128*4 = 8.4 MB

    k1_weights<<<(128 * 128) / 256, 256, 0, stream>>>(wq, wk, M);
    k2_t<<<B / RPB, 256, 0, stream>>>(state, M, t);
    k3_scores<<<(n_nodes * 8 + 255) / 256, 256, 0, stream>>>(action, t, rev, out, n_nodes);
}